// Round 1
// 324.092 us; speedup vs baseline: 1.0140x; 1.0140x over previous
//
#include <hip/hip_runtime.h>
#include <cstdint>

#define B_ 16
#define H_ 224
#define W_ 224
#define C_ 32
#define HW_ (H_*W_)            // 50176
#define NTOT_ ((size_t)B_*HW_*C_)
#define TILES_PER_B (HW_/32)   // 1568

__device__ __forceinline__ unsigned int enc_f32(float f) {
    unsigned int u = __float_as_uint(f);
    return (u & 0x80000000u) ? ~u : (u | 0x80000000u);
}
__device__ __forceinline__ float dec_f32(unsigned int u) {
    unsigned int v = (u & 0x80000000u) ? (u & 0x7fffffffu) : ~u;
    return __uint_as_float(v);
}

__global__ void k_init(unsigned int* scratch) {
    int t = threadIdx.x;
    if (t < B_) { scratch[t] = 0xFFFFFFFFu; scratch[B_ + t] = 0u; }
}

// K1: NHWC -> NCHW transpose + per-sample min/max (1 atomic pair per block).
// (unchanged from R3 for clean attribution of the remaining ~230us)
__global__ __launch_bounds__(256) void k_transpose_minmax(
        const float* __restrict__ x, float* __restrict__ xt,
        unsigned int* __restrict__ scratch) {
    __shared__ float tile[32][33];
    __shared__ float rmin[4], rmax[4];
    int t = threadIdx.x;
    int b = blockIdx.y;
    const float4* xb4 = (const float4*)(x + (size_t)b * HW_ * C_);
    float* xtb = xt + (size_t)b * C_ * HW_;
    float vmin = 1e30f, vmax = -1e30f;
    int lrow = t >> 3, lc4 = (t & 7) * 4;
    int wc = t >> 3, ww4 = (t & 7) * 4;

    for (int tile_i = blockIdx.x; tile_i < TILES_PER_B; tile_i += gridDim.x) {
        int hw0 = tile_i * 32;
        float4 v = xb4[(size_t)hw0 * C_ / 4 + t];
        vmin = fminf(vmin, fminf(fminf(v.x, v.y), fminf(v.z, v.w)));
        vmax = fmaxf(vmax, fmaxf(fmaxf(v.x, v.y), fmaxf(v.z, v.w)));
        tile[lrow][lc4+0] = v.x; tile[lrow][lc4+1] = v.y;
        tile[lrow][lc4+2] = v.z; tile[lrow][lc4+3] = v.w;
        __syncthreads();
        float4 o;
        o.x = tile[ww4+0][wc]; o.y = tile[ww4+1][wc];
        o.z = tile[ww4+2][wc]; o.w = tile[ww4+3][wc];
        *(float4*)(xtb + (size_t)wc * HW_ + hw0 + ww4) = o;
        __syncthreads();
    }
    for (int off = 32; off; off >>= 1) {
        vmin = fminf(vmin, __shfl_down(vmin, off));
        vmax = fmaxf(vmax, __shfl_down(vmax, off));
    }
    int wave = t >> 6;
    if ((t & 63) == 0) { rmin[wave] = vmin; rmax[wave] = vmax; }
    __syncthreads();
    if (t == 0) {
        float m0 = fminf(fminf(rmin[0], rmin[1]), fminf(rmin[2], rmin[3]));
        float m1 = fmaxf(fmaxf(rmax[0], rmax[1]), fmaxf(rmax[2], rmax[3]));
        atomicMin(&scratch[b], enc_f32(m0));
        atomicMax(&scratch[B_ + b], enc_f32(m1));
    }
}

// K3 v6: same row-streaming pipeline as v5 (depth 8, zero LDS), but H split
// into 7 chunks of 32 rows instead of 2 halves of 112.
// v5 was latency-bound, not throughput-bound: 2048 waves = 2 waves/SIMD
// (OccupancyPercent 19, VALUBusy 33, HBM 22%) and the per-iteration
// load->shfl->add->...->log chain has ~300cy of latency vs ~150cy of issue.
// 7 chunks -> 7168 wave-tasks = 7 waves/SIMD (64 VGPR x 7 = 448 <= 512).
// Warmup overhead rises to 16/48 iters (1.31x issue work) but buys ~3x
// latency hiding. h0 = chunk*32 keeps h0 % 8 == 0 so the acc-ring phases
// stay compile-time constants under the unroll-8.
__global__ __launch_bounds__(256) void k_alpha(
        const float* __restrict__ xt, float* __restrict__ at,
        const unsigned int* __restrict__ scratch) {
    const int wid  = threadIdx.x >> 6;
    const int lane = threadIdx.x & 63;
    int task  = blockIdx.x * 4 + wid;      // 7168 tasks: plane x strip x chunk
    int plane = task / 14;
    int rem   = task - plane * 14;
    int strip = rem & 1;
    int chunk = rem >> 1;                  // 0..6
    int b     = plane >> 5;
    const float* P = xt + (size_t)plane * HW_;
    float* Q = at + (size_t)plane * HW_;
    float mn  = dec_f32(scratch[b]);
    float mx  = dec_f32(scratch[B_ + b]);
    float inv = 1.0f / (mx - mn + 1e-7f);
    float minv = mn * inv;
    int sbase = strip * 112;
    int c0 = sbase - 8 + 2 * lane;
    int c1 = c0 + 1;
    int h0 = chunk * 32;                   // 0,32,...,192 -- all % 8 == 0
    int cl = min(max(c0, 0), W_ - 2);
    bool mC = (c0 >= 0) && (c0 <= W_ - 2); // c0 even -> c0,c1 both valid iff this
    bool laneok = (lane >= 4) && (lane <= 59);

    // per-column W-direction valid counts and folded constants
    float cw2_0  = (float)(min(c0+1, W_-1) - c0 + 1);
    float cw2_1  = (float)(min(c1+1, W_-1) - c1 + 1);
    float cw4_0  = (float)(min(c0+2, W_-1) - max(c0-1, 0) + 1);
    float cw4_1  = (float)(min(c1+2, W_-1) - max(c1-1, 0) + 1);
    float cw8_0  = (float)(min(c0+4, W_-1) - max(c0-3, 0) + 1);
    float cw8_1  = (float)(min(c1+4, W_-1) - max(c1-3, 0) + 1);
    float cw16_0 = (float)(min(c0+8, W_-1) - max(c0-7, 0) + 1);
    float cw16_1 = (float)(min(c1+8, W_-1) - max(c1-7, 0) + 1);
    float e2_0  = minv * cw2_0,  e2_1  = minv * cw2_1;
    float e4_0  = minv * cw4_0,  e4_1  = minv * cw4_1;
    float e8_0  = minv * cw8_0,  e8_1  = minv * cw8_1;
    float e16_0 = minv * cw16_0, e16_1 = minv * cw16_1;
    // interior rows: ch = 2/4/8/16 constant -> fold into additive constant
    float d2_0  = 1e-7f -  2.0f * e2_0,  d2_1  = 1e-7f -  2.0f * e2_1;
    float d4_0  = 1e-7f -  4.0f * e4_0,  d4_1  = 1e-7f -  4.0f * e4_1;
    float d8_0  = 1e-7f -  8.0f * e8_0,  d8_1  = 1e-7f -  8.0f * e8_1;
    float d16_0 = 1e-7f - 16.0f * e16_0, d16_1 = 1e-7f - 16.0f * e16_1;

    float hp0 = 0.f, hp1 = 0.f;            // Xh[a-1]
    float rB4[2][2]  = {};                 // [col][phase] delay-2
    float rB8[2][4]  = {};                 // delay-4
    float rB16[2][8] = {};                 // delay-8
    float acc[2][8]  = {};                 // alpha partials, slot = out_row & 7

    for (int it8 = 0; it8 < 6; ++it8) {    // 48 iters: 16 warmup + 32 rows
        #pragma unroll
        for (int u = 0; u < 8; ++u) {
            int it = it8 * 8 + u;
            int a = h0 - 7 + it;           // absolute input row
            float x0 = 0.f, x1 = 0.f;
            if (a >= 0 && a < H_) {        // wave-uniform branch
                float2 v = *(const float2*)(P + (size_t)a * W_ + cl);
                x0 = mC ? v.x : 0.f;
                x1 = mC ? v.y : 0.f;
            }
            // level 1 H (span 1)
            float nx0 = __shfl_down(x0, 1);
            float xh0 = x0 + x1;
            float xh1 = x1 + nx0;
            // level 1 V -> G2done[a-1] (col-aligned for out)
            float g2_0 = hp0 + xh0; hp0 = xh0;
            float g2_1 = hp1 + xh1; hp1 = xh1;
            // level 2 H (span 2 = next even/odd col)
            float b4n_0 = g2_0 + __shfl_down(g2_0, 1);
            float b4n_1 = g2_1 + __shfl_down(g2_1, 1);
            // level 2 V: A4done[a-3] = B4[a-3] + B4[a-1]
            float a4_0 = rB4[0][u & 1] + b4n_0; rB4[0][u & 1] = b4n_0;
            float a4_1 = rB4[1][u & 1] + b4n_1; rB4[1][u & 1] = b4n_1;
            // level 3 H (span 4 = 2 lanes)
            float b8n_0 = a4_0 + __shfl_down(a4_0, 2);
            float b8n_1 = a4_1 + __shfl_down(a4_1, 2);
            // level 3 V: A8done[a-7] = B8[a-7] + B8[a-3]
            float a8_0 = rB8[0][u & 3] + b8n_0; rB8[0][u & 3] = b8n_0;
            float a8_1 = rB8[1][u & 3] + b8n_1; rB8[1][u & 3] = b8n_1;
            // level 4 H (span 8 = 4 lanes)
            float b16n_0 = a8_0 + __shfl_down(a8_0, 4);
            float b16n_1 = a8_1 + __shfl_down(a8_1, 4);
            // level 4 V: A16done[a-15] = B16[a-15] + B16[a-7]
            float a16_0 = rB16[0][u] + b16n_0; rB16[0][u] = b16n_0;
            float a16_1 = rB16[1][u] + b16n_1; rB16[1][u] = b16n_1;
            // realign to output columns (window left-offsets 1/3/7)
            float g4_0  = __shfl_up(a4_1, 1);
            float g4_1  = a4_0;
            float g8_0  = __shfl_up(a8_1, 2);
            float g8_1  = __shfl_up(a8_0, 1);
            float g16_0 = __shfl_up(a16_1, 4);
            float g16_1 = __shfl_up(a16_0, 3);

            float l1_0, l1_1, l2_0, l2_1, l3_0, l3_1, l4_0, l4_1;
            if (a >= 15 && a <= 223) {     // all 4 row-counts unclamped
                l1_0 = __log2f(fmaxf(fmaf(g2_0,  inv, d2_0 ), 1e-7f));
                l1_1 = __log2f(fmaxf(fmaf(g2_1,  inv, d2_1 ), 1e-7f));
                l2_0 = __log2f(fmaxf(fmaf(g4_0,  inv, d4_0 ), 1e-7f));
                l2_1 = __log2f(fmaxf(fmaf(g4_1,  inv, d4_1 ), 1e-7f));
                l3_0 = __log2f(fmaxf(fmaf(g8_0,  inv, d8_0 ), 1e-7f));
                l3_1 = __log2f(fmaxf(fmaf(g8_1,  inv, d8_1 ), 1e-7f));
                l4_0 = __log2f(fmaxf(fmaf(g16_0, inv, d16_0), 1e-7f));
                l4_1 = __log2f(fmaxf(fmaf(g16_1, inv, d16_1), 1e-7f));
            } else {
                int o1 = a - 1, o2 = a - 2, o3 = a - 4, o4 = a - 8;
                float ch2  = (float)(min(o1+1, H_-1) - o1 + 1);
                float ch4  = (float)(min(o2+2, H_-1) - max(o2-1, 0) + 1);
                float ch8  = (float)(min(o3+4, H_-1) - max(o3-3, 0) + 1);
                float ch16 = (float)(min(o4+8, H_-1) - max(o4-7, 0) + 1);
                l1_0 = __log2f(fmaxf(fmaf(-e2_0,  ch2,  fmaf(g2_0,  inv, 1e-7f)), 1e-7f));
                l1_1 = __log2f(fmaxf(fmaf(-e2_1,  ch2,  fmaf(g2_1,  inv, 1e-7f)), 1e-7f));
                l2_0 = __log2f(fmaxf(fmaf(-e4_0,  ch4,  fmaf(g4_0,  inv, 1e-7f)), 1e-7f));
                l2_1 = __log2f(fmaxf(fmaf(-e4_1,  ch4,  fmaf(g4_1,  inv, 1e-7f)), 1e-7f));
                l3_0 = __log2f(fmaxf(fmaf(-e8_0,  ch8,  fmaf(g8_0,  inv, 1e-7f)), 1e-7f));
                l3_1 = __log2f(fmaxf(fmaf(-e8_1,  ch8,  fmaf(g8_1,  inv, 1e-7f)), 1e-7f));
                l4_0 = __log2f(fmaxf(fmaf(-e16_0, ch16, fmaf(g16_0, inv, 1e-7f)), 1e-7f));
                l4_1 = __log2f(fmaxf(fmaf(-e16_1, ch16, fmaf(g16_1, inv, 1e-7f)), 1e-7f));
            }
            // accumulate into per-out-row slots (all distinct mod 8)
            acc[0][u] = -0.3f * l1_0;                    // row a-1: init
            acc[1][u] = -0.3f * l1_1;
            acc[0][(u+7)&7] = fmaf(-0.1f, l2_0, acc[0][(u+7)&7]);  // row a-2
            acc[1][(u+7)&7] = fmaf(-0.1f, l2_1, acc[1][(u+7)&7]);
            acc[0][(u+5)&7] = fmaf( 0.1f, l3_0, acc[0][(u+5)&7]);  // row a-4
            acc[1][(u+5)&7] = fmaf( 0.1f, l3_1, acc[1][(u+5)&7]);
            int o = a - 8;                               // emit row
            if (o >= h0 && o <= h0 + 31) {               // wave-uniform
                float al0 = fmaf(0.3f, l4_0, acc[0][(u+1)&7]);
                float al1 = fmaf(0.3f, l4_1, acc[1][(u+1)&7]);
                if (laneok) {
                    float2 st; st.x = al0; st.y = al1;
                    *(float2*)(Q + (size_t)o * W_ + c0) = st;
                }
            }
        }
    }
}

// K4: NCHW alpha -> NHWC out with BatchNorm. (unchanged from R3)
__global__ __launch_bounds__(256) void k_out(
        const float* __restrict__ at,
        const float* __restrict__ gamma, const float* __restrict__ beta,
        const float* __restrict__ mmean, const float* __restrict__ mvar,
        float* __restrict__ out) {
    __shared__ float tile[32][33];
    __shared__ float s_scale[32], s_bias[32];
    int t = threadIdx.x;
    if (t < 32) {
        float sc = gamma[t] * rsqrtf(mvar[t] + 1e-3f);
        s_scale[t] = sc;
        s_bias[t]  = beta[t] - mmean[t] * sc;
    }
    __syncthreads();
    int rc = t >> 3, rw4 = (t & 7) * 4;
    int wrow = t >> 3, wc4 = (t & 7) * 4;

    for (int tidx = blockIdx.x; tidx < B_ * TILES_PER_B; tidx += gridDim.x) {
        int b = tidx / TILES_PER_B;
        int hw0 = (tidx - b * TILES_PER_B) * 32;
        const float* ab = at + (size_t)b * C_ * HW_;
        float4 v = *(const float4*)(ab + (size_t)rc * HW_ + hw0 + rw4);
        tile[rw4+0][rc] = v.x; tile[rw4+1][rc] = v.y;
        tile[rw4+2][rc] = v.z; tile[rw4+3][rc] = v.w;
        __syncthreads();
        float4 o;
        o.x = tile[wrow][wc4+0] * s_scale[wc4+0] + s_bias[wc4+0];
        o.y = tile[wrow][wc4+1] * s_scale[wc4+1] + s_bias[wc4+1];
        o.z = tile[wrow][wc4+2] * s_scale[wc4+2] + s_bias[wc4+2];
        o.w = tile[wrow][wc4+3] * s_scale[wc4+3] + s_bias[wc4+3];
        *(float4*)(out + ((size_t)b * HW_ + hw0 + wrow) * C_ + wc4) = o;
        __syncthreads();
    }
}

extern "C" void kernel_launch(void* const* d_in, const int* in_sizes, int n_in,
                              void* d_out, int out_size, void* d_ws, size_t ws_size,
                              hipStream_t stream) {
    const float* x     = (const float*)d_in[0];
    const float* gamma = (const float*)d_in[1];
    const float* beta  = (const float*)d_in[2];
    const float* mmean = (const float*)d_in[3];
    const float* mvar  = (const float*)d_in[4];
    float* out = (float*)d_out;

    float* xt = (float*)d_ws;                 // NCHW staging, NTOT_ floats
    float* at = xt + NTOT_;                   // NCHW alphas,  NTOT_ floats
    unsigned int* scratch = (unsigned int*)(at + NTOT_);  // 32 uints

    k_init<<<1, 64, 0, stream>>>(scratch);
    k_transpose_minmax<<<dim3(128, B_), 256, 0, stream>>>(x, xt, scratch);
    k_alpha<<<1792, 256, 0, stream>>>(xt, at, scratch);   // 7168 wave-tasks
    k_out<<<2048, 256, 0, stream>>>(at, gamma, beta, mmean, mvar, out);
}

// Round 2
// 308.928 us; speedup vs baseline: 1.0638x; 1.0491x over previous
//
#include <hip/hip_runtime.h>
#include <cstdint>

#define B_ 16
#define H_ 224
#define W_ 224
#define C_ 32
#define HW_ (H_*W_)            // 50176

__device__ __forceinline__ unsigned int enc_f32(float f) {
    unsigned int u = __float_as_uint(f);
    return (u & 0x80000000u) ? ~u : (u | 0x80000000u);
}
__device__ __forceinline__ float dec_f32(unsigned int u) {
    unsigned int v = (u & 0x80000000u) ? (u & 0x7fffffffu) : ~u;
    return __uint_as_float(v);
}

__global__ void k_init(unsigned int* scratch) {
    int t = threadIdx.x;
    if (t < B_) { scratch[t] = 0xFFFFFFFFu; scratch[B_ + t] = 0u; }
}

// K1 v2: pure streaming per-sample min/max over NHWC x (no transpose).
__global__ __launch_bounds__(256) void k_minmax(
        const float* __restrict__ x, unsigned int* __restrict__ scratch) {
    __shared__ float rmin[4], rmax[4];
    int t = threadIdx.x;
    int b = blockIdx.y;
    const float4* p = (const float4*)(x + (size_t)b * HW_ * C_);
    const int n4 = HW_ * C_ / 4;   // 401408
    float vmin = 1e30f, vmax = -1e30f;
    for (int i = blockIdx.x * 256 + t; i < n4; i += gridDim.x * 256) {
        float4 v = p[i];
        vmin = fminf(vmin, fminf(fminf(v.x, v.y), fminf(v.z, v.w)));
        vmax = fmaxf(vmax, fmaxf(fmaxf(v.x, v.y), fmaxf(v.z, v.w)));
    }
    for (int off = 32; off; off >>= 1) {
        vmin = fminf(vmin, __shfl_down(vmin, off));
        vmax = fmaxf(vmax, __shfl_down(vmax, off));
    }
    if ((t & 63) == 0) { rmin[t >> 6] = vmin; rmax[t >> 6] = vmax; }
    __syncthreads();
    if (t == 0) {
        atomicMin(&scratch[b],      enc_f32(fminf(fminf(rmin[0], rmin[1]), fminf(rmin[2], rmin[3]))));
        atomicMax(&scratch[B_ + b], enc_f32(fmaxf(fmaxf(rmax[0], rmax[1]), fmaxf(rmax[2], rmax[3]))));
    }
}

// K2 (fused): NHWC in -> NHWC out, no transposes, BN folded in.
// Block = 512 threads = 8 waves; wave wid owns channel c = cg*8+wid and runs
// the proven v6 row-streaming pipeline (depth-8 rings, lane = 2 columns).
// Per row: coop load 8-ch slice of the NHWC row (float2/thread) -> LDS
// [ch][132] (b64 reads stride 8B/lane: conflict-free) -> pipeline compute ->
// BN'd alphas to out-LDS -> coop float2 store of the PREVIOUS emitted row to
// NHWC out. Double-buffered LDS both directions, one __syncthreads per row.
// Depth-2 register queue (q0,q1; load row a+3 while staging a+1) hides
// global latency; __launch_bounds__(512,4) allows 128 VGPR (state ~90).
__global__ __launch_bounds__(512, 4) void k_fused(
        const float* __restrict__ x, float* __restrict__ out,
        const float* __restrict__ gamma, const float* __restrict__ beta,
        const float* __restrict__ mmean, const float* __restrict__ mvar,
        const unsigned int* __restrict__ scratch) {
    __shared__ float lin[2][8][132];
    __shared__ float lout[2][8][132];
    const int t    = threadIdx.x;
    const int wid  = t >> 6;
    const int lane = t & 63;

    int bid   = blockIdx.x;            // ((b*4 + chunk)*2 + strip)*4 + cg
    int cg    = bid & 3;
    int strip = (bid >> 2) & 1;
    int chunk = (bid >> 3) & 3;
    int b     = bid >> 5;

    const int c     = cg * 8 + wid;    // this wave's channel
    const int cbase = cg * 8;
    const int h0    = chunk * 56;      // 56 % 8 == 0: ring phases intact
    const int sbase = strip * 112;

    // BN constants (wave-uniform)
    float sc = gamma[c] * rsqrtf(mvar[c] + 1e-3f);
    float bi = beta[c] - mmean[c] * sc;

    float mn   = dec_f32(scratch[b]);
    float mx   = dec_f32(scratch[B_ + b]);
    float inv  = 1.0f / (mx - mn + 1e-7f);
    float minv = mn * inv;

    // pipeline-lane column mapping (identical to v6)
    int c0 = sbase - 8 + 2 * lane;
    int c1 = c0 + 1;
    bool mC = (c0 >= 0) && (c0 <= W_ - 2);

    // loader/storer mapping
    int col_l = t >> 2;                        // 0..127
    int lch   = (t & 3) * 2;                   // 0,2,4,6
    int wld   = min(max(sbase - 8 + col_l, 0), W_ - 1);
    int wst   = sbase - 8 + col_l;             // valid when colok
    bool colok = (col_l >= 8) && (col_l < 120);
    const float* xb = x   + (size_t)b * HW_ * C_ + cbase + lch;
    float*       ob = out + (size_t)b * HW_ * C_ + cbase + lch;

    // per-column W-direction valid counts and folded constants (as v6)
    float cw2_0  = (float)(min(c0+1, W_-1) - c0 + 1);
    float cw2_1  = (float)(min(c1+1, W_-1) - c1 + 1);
    float cw4_0  = (float)(min(c0+2, W_-1) - max(c0-1, 0) + 1);
    float cw4_1  = (float)(min(c1+2, W_-1) - max(c1-1, 0) + 1);
    float cw8_0  = (float)(min(c0+4, W_-1) - max(c0-3, 0) + 1);
    float cw8_1  = (float)(min(c1+4, W_-1) - max(c1-3, 0) + 1);
    float cw16_0 = (float)(min(c0+8, W_-1) - max(c0-7, 0) + 1);
    float cw16_1 = (float)(min(c1+8, W_-1) - max(c1-7, 0) + 1);
    float e2_0  = minv * cw2_0,  e2_1  = minv * cw2_1;
    float e4_0  = minv * cw4_0,  e4_1  = minv * cw4_1;
    float e8_0  = minv * cw8_0,  e8_1  = minv * cw8_1;
    float e16_0 = minv * cw16_0, e16_1 = minv * cw16_1;
    float d2_0  = 1e-7f -  2.0f * e2_0,  d2_1  = 1e-7f -  2.0f * e2_1;
    float d4_0  = 1e-7f -  4.0f * e4_0,  d4_1  = 1e-7f -  4.0f * e4_1;
    float d8_0  = 1e-7f -  8.0f * e8_0,  d8_1  = 1e-7f -  8.0f * e8_1;
    float d16_0 = 1e-7f - 16.0f * e16_0, d16_1 = 1e-7f - 16.0f * e16_1;

    float hp0 = 0.f, hp1 = 0.f;            // Xh[a-1]
    float rB4[2][2]  = {};                 // delay-2
    float rB8[2][4]  = {};                 // delay-4
    float rB16[2][8] = {};                 // delay-8
    float acc[2][8]  = {};                 // alpha partials, slot = out_row & 7

#define LDROW(AR) (*(const float2*)(xb + (size_t)((min(max((AR), 0), H_-1)) * W_ + wld) * C_))

    // prologue: stage row h0-7 into lin[1] (read by it=0); preload q0,q1
    float2 q0, q1;
    {
        float2 qi = LDROW(h0 - 7);
        lin[1][lch][col_l]     = qi.x;
        lin[1][lch + 1][col_l] = qi.y;
        q0 = LDROW(h0 - 6);
        q1 = LDROW(h0 - 5);
    }

    for (int g8 = 0; g8 < 9; ++g8) {       // 72 iters: 16 warmup + 56 rows
        #pragma unroll
        for (int u = 0; u < 8; ++u) {
            int it = g8 * 8 + u;
            int a  = h0 - 7 + it;          // absolute input row
            __syncthreads();
            // this row (staged last iter): buffer (u+1)&1
            float2 lv = *(const float2*)&lin[(u + 1) & 1][wid][2 * lane];
            // stage next row a+1 into buffer u&1
            lin[u & 1][lch][col_l]     = q0.x;
            lin[u & 1][lch + 1][col_l] = q0.y;
            q0 = q1;
            q1 = LDROW(a + 3);
            // coop store of the row emitted LAST iter (from lout[u&1])
            if (it >= 16 && colok) {
                int op = h0 - 16 + it;
                float2 sv;
                sv.x = lout[u & 1][lch][col_l];
                sv.y = lout[u & 1][lch + 1][col_l];
                *(float2*)(ob + (size_t)(op * W_ + wst) * C_) = sv;
            }

            bool rowok = (a >= 0) && (a < H_);
            float x0 = (rowok && mC) ? lv.x : 0.f;
            float x1 = (rowok && mC) ? lv.y : 0.f;
            // level 1 H (span 1)
            float nx0 = __shfl_down(x0, 1);
            float xh0 = x0 + x1;
            float xh1 = x1 + nx0;
            // level 1 V -> G2done[a-1]
            float g2_0 = hp0 + xh0; hp0 = xh0;
            float g2_1 = hp1 + xh1; hp1 = xh1;
            // level 2 H (span 2)
            float b4n_0 = g2_0 + __shfl_down(g2_0, 1);
            float b4n_1 = g2_1 + __shfl_down(g2_1, 1);
            // level 2 V
            float a4_0 = rB4[0][u & 1] + b4n_0; rB4[0][u & 1] = b4n_0;
            float a4_1 = rB4[1][u & 1] + b4n_1; rB4[1][u & 1] = b4n_1;
            // level 3 H (span 4)
            float b8n_0 = a4_0 + __shfl_down(a4_0, 2);
            float b8n_1 = a4_1 + __shfl_down(a4_1, 2);
            // level 3 V
            float a8_0 = rB8[0][u & 3] + b8n_0; rB8[0][u & 3] = b8n_0;
            float a8_1 = rB8[1][u & 3] + b8n_1; rB8[1][u & 3] = b8n_1;
            // level 4 H (span 8)
            float b16n_0 = a8_0 + __shfl_down(a8_0, 4);
            float b16n_1 = a8_1 + __shfl_down(a8_1, 4);
            // level 4 V
            float a16_0 = rB16[0][u] + b16n_0; rB16[0][u] = b16n_0;
            float a16_1 = rB16[1][u] + b16n_1; rB16[1][u] = b16n_1;
            // realign to output columns (window left-offsets 1/3/7)
            float g4_0  = __shfl_up(a4_1, 1);
            float g4_1  = a4_0;
            float g8_0  = __shfl_up(a8_1, 2);
            float g8_1  = __shfl_up(a8_0, 1);
            float g16_0 = __shfl_up(a16_1, 4);
            float g16_1 = __shfl_up(a16_0, 3);

            float l1_0, l1_1, l2_0, l2_1, l3_0, l3_1, l4_0, l4_1;
            if (a >= 15 && a <= 223) {     // all 4 row-counts unclamped
                l1_0 = __log2f(fmaxf(fmaf(g2_0,  inv, d2_0 ), 1e-7f));
                l1_1 = __log2f(fmaxf(fmaf(g2_1,  inv, d2_1 ), 1e-7f));
                l2_0 = __log2f(fmaxf(fmaf(g4_0,  inv, d4_0 ), 1e-7f));
                l2_1 = __log2f(fmaxf(fmaf(g4_1,  inv, d4_1 ), 1e-7f));
                l3_0 = __log2f(fmaxf(fmaf(g8_0,  inv, d8_0 ), 1e-7f));
                l3_1 = __log2f(fmaxf(fmaf(g8_1,  inv, d8_1 ), 1e-7f));
                l4_0 = __log2f(fmaxf(fmaf(g16_0, inv, d16_0), 1e-7f));
                l4_1 = __log2f(fmaxf(fmaf(g16_1, inv, d16_1), 1e-7f));
            } else {
                int o1 = a - 1, o2 = a - 2, o3 = a - 4, o4 = a - 8;
                float ch2  = (float)(min(o1+1, H_-1) - o1 + 1);
                float ch4  = (float)(min(o2+2, H_-1) - max(o2-1, 0) + 1);
                float ch8  = (float)(min(o3+4, H_-1) - max(o3-3, 0) + 1);
                float ch16 = (float)(min(o4+8, H_-1) - max(o4-7, 0) + 1);
                l1_0 = __log2f(fmaxf(fmaf(-e2_0,  ch2,  fmaf(g2_0,  inv, 1e-7f)), 1e-7f));
                l1_1 = __log2f(fmaxf(fmaf(-e2_1,  ch2,  fmaf(g2_1,  inv, 1e-7f)), 1e-7f));
                l2_0 = __log2f(fmaxf(fmaf(-e4_0,  ch4,  fmaf(g4_0,  inv, 1e-7f)), 1e-7f));
                l2_1 = __log2f(fmaxf(fmaf(-e4_1,  ch4,  fmaf(g4_1,  inv, 1e-7f)), 1e-7f));
                l3_0 = __log2f(fmaxf(fmaf(-e8_0,  ch8,  fmaf(g8_0,  inv, 1e-7f)), 1e-7f));
                l3_1 = __log2f(fmaxf(fmaf(-e8_1,  ch8,  fmaf(g8_1,  inv, 1e-7f)), 1e-7f));
                l4_0 = __log2f(fmaxf(fmaf(-e16_0, ch16, fmaf(g16_0, inv, 1e-7f)), 1e-7f));
                l4_1 = __log2f(fmaxf(fmaf(-e16_1, ch16, fmaf(g16_1, inv, 1e-7f)), 1e-7f));
            }
            // accumulate into per-out-row slots (all distinct mod 8)
            acc[0][u] = -0.3f * l1_0;                    // row a-1: init
            acc[1][u] = -0.3f * l1_1;
            acc[0][(u+7)&7] = fmaf(-0.1f, l2_0, acc[0][(u+7)&7]);  // row a-2
            acc[1][(u+7)&7] = fmaf(-0.1f, l2_1, acc[1][(u+7)&7]);
            acc[0][(u+5)&7] = fmaf( 0.1f, l3_0, acc[0][(u+5)&7]);  // row a-4
            acc[1][(u+5)&7] = fmaf( 0.1f, l3_1, acc[1][(u+5)&7]);
            // emit row o = a-8 (it in [15,70]) -> BN -> out-LDS buffer (u+1)&1
            if (it >= 15 && it <= 70) {
                float al0 = fmaf(0.3f, l4_0, acc[0][(u+1)&7]);
                float al1 = fmaf(0.3f, l4_1, acc[1][(u+1)&7]);
                float2 ev;
                ev.x = fmaf(sc, al0, bi);
                ev.y = fmaf(sc, al1, bi);
                *(float2*)&lout[(u + 1) & 1][wid][2 * lane] = ev;
            }
        }
    }
#undef LDROW
}

extern "C" void kernel_launch(void* const* d_in, const int* in_sizes, int n_in,
                              void* d_out, int out_size, void* d_ws, size_t ws_size,
                              hipStream_t stream) {
    const float* x     = (const float*)d_in[0];
    const float* gamma = (const float*)d_in[1];
    const float* beta  = (const float*)d_in[2];
    const float* mmean = (const float*)d_in[3];
    const float* mvar  = (const float*)d_in[4];
    float* out = (float*)d_out;

    unsigned int* scratch = (unsigned int*)d_ws;  // 32 uints

    k_init<<<1, 64, 0, stream>>>(scratch);
    k_minmax<<<dim3(128, B_), 256, 0, stream>>>(x, scratch);
    k_fused<<<512, 512, 0, stream>>>(x, out, gamma, beta, mmean, mvar, scratch);
}